// Round 4
// baseline (219.589 us; speedup 1.0000x reference)
//
#include <hip/hip_runtime.h>
#include <stdint.h>

#define BB 32
#define TT 512
#define DD 1024
#define NN 65536
#define HH 150
#define LL 17

typedef __bf16 bf16_t;
typedef short shortx8 __attribute__((ext_vector_type(8)));
typedef float f32x4 __attribute__((ext_vector_type(4)));

static __device__ __forceinline__ short f2bf(float f) {
  return (short)__builtin_bit_cast(unsigned short, (bf16_t)f);
}

// ---------------------------------------------------------------------------
// Prep: repack W1 into MFMA B-fragment layout Bp[64 kb][10 cb][64 lane][8 j]
// (value = W1[kb*32 + (l>>4)*8 + j][cb*16 + (l&15)], zero-padded cols>=150)
// and W2 into W2p[5 kb][2 cb][64 lane][8 j] (zero-padded rows>=150, cols>=17).
// Must re-run every launch: d_ws is re-poisoned before each timed call.
// ---------------------------------------------------------------------------
__global__ __launch_bounds__(256) void prep_repack(
    const float* __restrict__ W1, const float* __restrict__ W2,
    short* __restrict__ Bp, short* __restrict__ W2p)
{
  int task = blockIdx.x * 256 + threadIdx.x;
  const int NW1 = 64 * 10 * 64;  // 40960 fragments of 16B
  if (task < NW1) {
    int kb  = task / 640;
    int rem = task - kb * 640;
    int cb = rem >> 6, l = rem & 63;
    int col  = cb * 16 + (l & 15);
    int krow = kb * 32 + (l >> 4) * 8;
    shortx8 v;
#pragma unroll
    for (int j = 0; j < 8; ++j) {
      float f = (col < HH) ? W1[(krow + j) * HH + col] : 0.f;
      v[j] = f2bf(f);
    }
    *reinterpret_cast<shortx8*>(Bp + task * 8) = v;
  } else if (task < NW1 + 640) {
    int t2 = task - NW1;
    int kb  = t2 >> 7;
    int rem = t2 & 127;
    int cb = rem >> 6, l = rem & 63;
    int col  = cb * 16 + (l & 15);
    int krow = kb * 32 + (l >> 4) * 8;
    shortx8 v;
#pragma unroll
    for (int j = 0; j < 8; ++j) {
      int r = krow + j;
      float f = (r < HH && col < LL) ? W2[r * LL + col] : 0.f;
      v[j] = f2bf(f);
    }
    *reinterpret_cast<shortx8*>(W2p + t2 * 8) = v;
  }
}

// ---------------------------------------------------------------------------
// Main kernel helpers
// ---------------------------------------------------------------------------
__device__ __forceinline__ void load_a_chunk(const float* const (&abase)[4][2],
                                             int c, int kg, f32x4 (&a)[4][2][2]) {
  // chunk c covers K-substeps ks = 2c, 2c+1 (K=32 each). Substeps 0..31 come
  // from span-begin row, 32..63 from span-end row (feats = concat).
#pragma unroll
  for (int rf = 0; rf < 4; ++rf) {
#pragma unroll
    for (int s = 0; s < 2; ++s) {
      int ks = 2 * c + s;
      const float* src = (ks < 32) ? abase[rf][0] : abase[rf][1];
      int off = (ks & 31) * 32 + kg * 8;  // float index within the xs row
      a[rf][s][0] = *reinterpret_cast<const f32x4*>(src + off);
      a[rf][s][1] = *reinterpret_cast<const f32x4*>(src + off + 4);
    }
  }
}

__device__ __forceinline__ shortx8 cvt_bf8(f32x4 x, f32x4 y) {
  shortx8 r;
  r[0] = f2bf(x[0]); r[1] = f2bf(x[1]); r[2] = f2bf(x[2]); r[3] = f2bf(x[3]);
  r[4] = f2bf(y[0]); r[5] = f2bf(y[1]); r[6] = f2bf(y[2]); r[7] = f2bf(y[3]);
  return r;
}

__device__ __forceinline__ void compute_chunk(const short* __restrict__ Bsbuf,
                                              int lane,
                                              const f32x4 (&a)[4][2][2],
                                              f32x4 (&acc)[4][10]) {
#pragma unroll
  for (int s = 0; s < 2; ++s) {
    shortx8 bfr[10];
#pragma unroll
    for (int cb = 0; cb < 10; ++cb)
      bfr[cb] = *reinterpret_cast<const shortx8*>(
          Bsbuf + ((s * 10 + cb) * 64 + lane) * 8);
#pragma unroll
    for (int rf = 0; rf < 4; ++rf) {
      shortx8 af = cvt_bf8(a[rf][s][0], a[rf][s][1]);
#pragma unroll
      for (int cb = 0; cb < 10; ++cb)
        acc[rf][cb] = __builtin_amdgcn_mfma_f32_16x16x32_bf16(
            af, bfr[cb], acc[rf][cb], 0, 0, 0);
    }
  }
}

// barrier that does NOT drain vmcnt: LDS hazards need lgkmcnt only; global
// prefetches (A regs + B stage regs) stay in flight across it.
#define BAR() do { \
    asm volatile("s_waitcnt lgkmcnt(0)" ::: "memory"); \
    __builtin_amdgcn_s_barrier(); \
  } while (0)

// ---------------------------------------------------------------------------
// Main: 256 blocks x 256 threads. Block owns 256 spans; wave owns 64 spans
// (4 row-frags of 16). GEMM1 K=2048 in 32 chunks of BK=64 (2 MFMA substeps).
// B double-buffered in LDS via reg-staging; A direct global->reg, 1-chunk
// prefetch. Epilogue: relu(acc+b1) -> bf16 h in LDS -> GEMM2 (K=160 padded,
// N=32 padded) -> out + b2.
// ---------------------------------------------------------------------------
__global__ __launch_bounds__(256, 1) void span_mlp(
    const float* __restrict__ xs, const int* __restrict__ spans,
    const int* __restrict__ bids, const short* __restrict__ Bp,
    const float* __restrict__ b1, const short* __restrict__ W2p,
    const float* __restrict__ b2, float* __restrict__ out)
{
  __shared__ __align__(16) char lds_raw[86016];  // max(2*20480 B-dbuf, 256*168*2 h)
  short* Bs = (short*)lds_raw;

  const int tid  = threadIdx.x;
  const int wv   = tid >> 6;
  const int lane = tid & 63;
  const int l15  = lane & 15;
  const int kg   = lane >> 4;
  const int blk  = blockIdx.x;

  // gathered A row base pointers (span begin / end) per row-frag
  const float* abase[4][2];
#pragma unroll
  for (int rf = 0; rf < 4; ++rf) {
    int r  = blk * 256 + wv * 64 + rf * 16 + l15;
    int b  = bids[r];
    int s0 = spans[2 * r + 0];
    int s1 = spans[2 * r + 1];
    abase[rf][0] = xs + (size_t)(b * TT + s0) * DD;
    abase[rf][1] = xs + (size_t)(b * TT + s1) * DD;
  }

  f32x4 acc[4][10];
  {
    f32x4 z = {0.f, 0.f, 0.f, 0.f};
#pragma unroll
    for (int rf = 0; rf < 4; ++rf)
#pragma unroll
      for (int cb = 0; cb < 10; ++cb) acc[rf][cb] = z;
  }

  uint4 breg[5];
  f32x4 abufA[4][2][2], abufB[4][2][2];

#define STAGE_LOAD(c) do { _Pragma("unroll") \
    for (int i = 0; i < 5; ++i) \
      breg[i] = *reinterpret_cast<const uint4*>(Bp + (c) * 10240 + tid * 8 + i * 2048); \
  } while (0)
#define STAGE_WRITE(p) do { _Pragma("unroll") \
    for (int i = 0; i < 5; ++i) \
      *reinterpret_cast<uint4*>(Bs + (p) * 10240 + tid * 8 + i * 2048) = breg[i]; \
  } while (0)

  // prologue: chunk 0
  STAGE_LOAD(0);
  load_a_chunk(abase, 0, kg, abufA);
  STAGE_WRITE(0);
  BAR();

  for (int cp = 0; cp < 16; ++cp) {
    int c0 = 2 * cp;
    // even chunk: compute buf0 / abufA, stage chunk c0+1 -> buf1
    STAGE_LOAD(c0 + 1);
    load_a_chunk(abase, c0 + 1, kg, abufB);
    compute_chunk(Bs, lane, abufA, acc);
    STAGE_WRITE(1);
    BAR();
    // odd chunk: compute buf1 / abufB, stage chunk c0+2 -> buf0
    if (cp < 15) {
      STAGE_LOAD(c0 + 2);
      load_a_chunk(abase, c0 + 2, kg, abufA);
    }
    compute_chunk(Bs + 10240, lane, abufB, acc);
    if (cp < 15) STAGE_WRITE(0);
    BAR();
  }

  // ---- epilogue: bias + relu -> h (bf16) in LDS [256][168] (padded stride)
  short* hS = (short*)lds_raw;
#pragma unroll
  for (int rf = 0; rf < 4; ++rf) {
#pragma unroll
    for (int cb = 0; cb < 10; ++cb) {
      int col = cb * 16 + l15;
      float bb = (col < HH) ? b1[col] : 0.f;
#pragma unroll
      for (int i = 0; i < 4; ++i) {
        int row = wv * 64 + rf * 16 + kg * 4 + i;   // C layout: row=(l>>4)*4+i
        float v = acc[rf][cb][i] + bb;
        v = fmaxf(v, 0.f);
        hS[row * 168 + col] = f2bf(v);
      }
    }
  }
  BAR();

  // ---- layer 2: [16 rows x K=160(pad)] @ W2p -> [16 x 32(pad)]
  f32x4 acc2[4][2];
  {
    f32x4 z = {0.f, 0.f, 0.f, 0.f};
#pragma unroll
    for (int rf = 0; rf < 4; ++rf) { acc2[rf][0] = z; acc2[rf][1] = z; }
  }
#pragma unroll
  for (int ks = 0; ks < 5; ++ks) {
#pragma unroll
    for (int cb2 = 0; cb2 < 2; ++cb2) {
      shortx8 wf = *reinterpret_cast<const shortx8*>(
          W2p + ((ks * 2 + cb2) * 64 + lane) * 8);
#pragma unroll
      for (int rf = 0; rf < 4; ++rf) {
        shortx8 af = *reinterpret_cast<const shortx8*>(
            hS + (wv * 64 + rf * 16 + l15) * 168 + ks * 32 + kg * 8);
        acc2[rf][cb2] = __builtin_amdgcn_mfma_f32_16x16x32_bf16(
            af, wf, acc2[rf][cb2], 0, 0, 0);
      }
    }
  }

  // ---- write scores (+b2)
#pragma unroll
  for (int rf = 0; rf < 4; ++rf) {
#pragma unroll
    for (int cb2 = 0; cb2 < 2; ++cb2) {
      int col = cb2 * 16 + l15;
      if (col < LL) {
        float bb = b2[col];
#pragma unroll
        for (int i = 0; i < 4; ++i) {
          int row = blk * 256 + wv * 64 + rf * 16 + kg * 4 + i;
          out[(size_t)row * LL + col] = acc2[rf][cb2][i] + bb;
        }
      }
    }
  }
#undef STAGE_LOAD
#undef STAGE_WRITE
}

extern "C" void kernel_launch(void* const* d_in, const int* in_sizes, int n_in,
                              void* d_out, int out_size, void* d_ws, size_t ws_size,
                              hipStream_t stream) {
  const float* xs    = (const float*)d_in[0];
  const int*   spans = (const int*)d_in[1];
  const int*   bids  = (const int*)d_in[2];
  const float* W1    = (const float*)d_in[3];
  const float* b1    = (const float*)d_in[4];
  const float* W2    = (const float*)d_in[5];
  const float* b2    = (const float*)d_in[6];
  float* out = (float*)d_out;

  short* Bp  = (short*)d_ws;            // 655360 B
  short* W2p = Bp + 40960 * 8;          // +10240 B  (total ws use: 665600 B)

  prep_repack<<<163, 256, 0, stream>>>(W1, W2, Bp, W2p);
  span_mlp<<<256, 256, 0, stream>>>(xs, spans, bids, Bp, b1, W2p, b2, out);
}

// Round 5
// 159.410 us; speedup vs baseline: 1.3775x; 1.3775x over previous
//
#include <hip/hip_runtime.h>
#include <stdint.h>

#define TT 512
#define DD 1024
#define NN 65536
#define HH 150
#define LL 17

typedef __bf16 bf16_t;
typedef short shortx8 __attribute__((ext_vector_type(8)));
typedef short shortx4 __attribute__((ext_vector_type(4)));
typedef float f32x4 __attribute__((ext_vector_type(4)));

typedef __attribute__((address_space(1))) const void gconst_void;
typedef __attribute__((address_space(3))) void lds_void;

static __device__ __forceinline__ short f2bf(float f) {
  return (short)__builtin_bit_cast(unsigned short, (bf16_t)f);
}

// ---------------------------------------------------------------------------
// Prep: (optional) xs fp32->bf16 (blocks 0..2047, 8 x float4 per thread, exact
// 16,777,216 elements), then W1 repack -> Bp[64 kb][10 cb][64 lane][8 j]
// (= W1[kb*32+(l>>4)*8+j][cb*16+(l&15)], zero-pad cols>=150) and W2 -> W2p.
// Re-run every launch: d_ws re-poisoned before each timed call.
// ---------------------------------------------------------------------------
__global__ __launch_bounds__(256) void prep_all(
    const float* __restrict__ xs, const float* __restrict__ W1,
    const float* __restrict__ W2, short* __restrict__ xs16,
    short* __restrict__ Bp, short* __restrict__ W2p, int do_cvt)
{
  int b = blockIdx.x;
  if (do_cvt && b < 2048) {
    int t = b * 256 + threadIdx.x;
#pragma unroll
    for (int i = 0; i < 8; ++i) {
      int id = t + i * 524288;              // float4 index, 4,194,304 total
      f32x4 v = reinterpret_cast<const f32x4*>(xs)[id];
      shortx4 o;
      o[0] = f2bf(v[0]); o[1] = f2bf(v[1]); o[2] = f2bf(v[2]); o[3] = f2bf(v[3]);
      reinterpret_cast<shortx4*>(xs16)[id] = o;
    }
    return;
  }
  int rb = do_cvt ? b - 2048 : b;
  int task = rb * 256 + threadIdx.x;
  const int NW1 = 64 * 10 * 64;             // 40960 fragments of 16B
  if (task < NW1) {
    int kb  = task / 640;
    int rem = task - kb * 640;
    int cb = rem >> 6, l = rem & 63;
    int col  = cb * 16 + (l & 15);
    int krow = kb * 32 + (l >> 4) * 8;
    shortx8 v;
#pragma unroll
    for (int j = 0; j < 8; ++j) {
      float f = (col < HH) ? W1[(krow + j) * HH + col] : 0.f;
      v[j] = f2bf(f);
    }
    *reinterpret_cast<shortx8*>(Bp + task * 8) = v;
  } else if (task < NW1 + 640) {
    int t2 = task - NW1;
    int kb  = t2 >> 7;
    int rem = t2 & 127;
    int cb = rem >> 6, l = rem & 63;
    int col  = cb * 16 + (l & 15);
    int krow = kb * 32 + (l >> 4) * 8;
    shortx8 v;
#pragma unroll
    for (int j = 0; j < 8; ++j) {
      int r = krow + j;
      float f = (r < HH && col < LL) ? W2[r * LL + col] : 0.f;
      v[j] = f2bf(f);
    }
    *reinterpret_cast<shortx8*>(W2p + t2 * 8) = v;
  }
}

// ---------------------------------------------------------------------------
// Main v2: 512 blocks x 256 threads (4 waves x 32 rows, rf=2). BK=64, 32
// chunks. B staged global_load_lds -> LDS dbuf (2 x 20KB) with counted
// vmcnt(N) + raw barrier (loads stay in flight across barriers). A gathered
// global->reg (bf16 if XS16 else fp32+cvt), 1-chunk prefetch. Epilogue:
// per-wave h region (32 x 168 shorts, 16B-aligned rows) -> GEMM2, no barriers.
// ---------------------------------------------------------------------------
__device__ __forceinline__ void stageB(const short* __restrict__ Bp, char* lds,
                                       int c, int p, int wv, int lane) {
#pragma unroll
  for (int i = 0; i < 5; ++i) {
    const char* g = (const char*)Bp + (size_t)c * 20480 + wv * 5120 + i * 1024 + lane * 16;
    char* l = lds + p * 20480 + wv * 5120 + i * 1024;   // wave-uniform dest
    __builtin_amdgcn_global_load_lds((gconst_void*)g, (lds_void*)l, 16, 0, 0);
  }
}

template<int XS16>
__device__ __forceinline__ void loadA(const char* const (&abase)[2][2], int c,
                                      int kg, shortx8 (&abuf)[2][2]) {
  const int side = (c >= 16) ? 1 : 0;       // feats = concat(begin,end): k<1024 begin
#pragma unroll
  for (int rf = 0; rf < 2; ++rf) {
#pragma unroll
    for (int s = 0; s < 2; ++s) {
      int ks31 = (2 * c + s) & 31;          // 32-k substep within the row
      if constexpr (XS16) {
        abuf[rf][s] = *reinterpret_cast<const shortx8*>(
            abase[rf][side] + ks31 * 64 + kg * 16);
      } else {
        f32x4 x = *reinterpret_cast<const f32x4*>(abase[rf][side] + ks31 * 128 + kg * 32);
        f32x4 y = *reinterpret_cast<const f32x4*>(abase[rf][side] + ks31 * 128 + kg * 32 + 16);
        shortx8 t;
        t[0]=f2bf(x[0]); t[1]=f2bf(x[1]); t[2]=f2bf(x[2]); t[3]=f2bf(x[3]);
        t[4]=f2bf(y[0]); t[5]=f2bf(y[1]); t[6]=f2bf(y[2]); t[7]=f2bf(y[3]);
        abuf[rf][s] = t;
      }
    }
  }
}

__device__ __forceinline__ void computeC(const char* lds, int p, int lane,
                                         const shortx8 (&abuf)[2][2],
                                         f32x4 (&acc)[2][10]) {
#pragma unroll
  for (int s = 0; s < 2; ++s) {
    shortx8 bfr[10];
#pragma unroll
    for (int cb = 0; cb < 10; ++cb)
      bfr[cb] = *reinterpret_cast<const shortx8*>(
          lds + p * 20480 + (s * 10 + cb) * 1024 + lane * 16);
#pragma unroll
    for (int rf = 0; rf < 2; ++rf)
#pragma unroll
      for (int cb = 0; cb < 10; ++cb)
        acc[rf][cb] = __builtin_amdgcn_mfma_f32_16x16x32_bf16(
            abuf[rf][s], bfr[cb], acc[rf][cb], 0, 0, 0);
  }
}

template<int XS16>
__global__ __launch_bounds__(256, 1) void span_mlp2(
    const void* __restrict__ xsv, const int* __restrict__ spans,
    const int* __restrict__ bids, const short* __restrict__ Bp,
    const float* __restrict__ b1, const short* __restrict__ W2p,
    const float* __restrict__ b2, float* __restrict__ out)
{
  // 43008 B = max(B-dbuf 40960, h-tile 4 x 32 x 168 x 2) -> 2-3 blocks/CU
  __shared__ __align__(16) char lds[43008];

  const int tid  = threadIdx.x;
  const int wv   = tid >> 6;
  const int lane = tid & 63;
  const int l15  = lane & 15;
  const int kg   = lane >> 4;
  const int blk  = blockIdx.x;

  // gathered A row base byte-pointers [rf][begin/end]
  const char* abase[2][2];
  const int elt = XS16 ? 2 : 4;
#pragma unroll
  for (int rf = 0; rf < 2; ++rf) {
    int r  = blk * 128 + wv * 32 + rf * 16 + l15;
    int bb = bids[r];
    int s0 = spans[2 * r + 0];
    int s1 = spans[2 * r + 1];
    abase[rf][0] = (const char*)xsv + (size_t)(bb * TT + s0) * DD * elt;
    abase[rf][1] = (const char*)xsv + (size_t)(bb * TT + s1) * DD * elt;
  }

  f32x4 acc[2][10];
  {
    f32x4 z = {0.f, 0.f, 0.f, 0.f};
#pragma unroll
    for (int rf = 0; rf < 2; ++rf)
#pragma unroll
      for (int cb = 0; cb < 10; ++cb) acc[rf][cb] = z;
  }

  shortx8 abufA[2][2], abufB[2][2];

  // counted-vmcnt barrier: 5 B-stage loads are the oldest outstanding; the
  // 4 (bf16) / 8 (fp32) A-loads may stay in flight across the barrier.
#define WAITSTAGE() do { \
    if constexpr (XS16) asm volatile("s_waitcnt vmcnt(4)" ::: "memory"); \
    else                asm volatile("s_waitcnt vmcnt(8)" ::: "memory"); \
    __builtin_amdgcn_s_barrier(); \
    __builtin_amdgcn_sched_barrier(0); \
  } while (0)

  // prologue: chunk 0
  stageB(Bp, lds, 0, 0, wv, lane);
  loadA<XS16>(abase, 0, kg, abufA);
  WAITSTAGE();

  for (int cp = 0; cp < 16; ++cp) {
    int c0 = 2 * cp;
    // even chunk: compute buf0/abufA, stage c0+1 -> buf1
    stageB(Bp, lds, c0 + 1, 1, wv, lane);
    loadA<XS16>(abase, c0 + 1, kg, abufB);
    computeC(lds, 0, lane, abufA, acc);
    WAITSTAGE();
    // odd chunk: compute buf1/abufB, stage c0+2 -> buf0
    if (cp < 15) {
      stageB(Bp, lds, c0 + 2, 0, wv, lane);
      loadA<XS16>(abase, c0 + 2, kg, abufA);
    }
    computeC(lds, 1, lane, abufB, acc);
    if (cp < 15) WAITSTAGE();
  }

  // ---- epilogue: full drain once, then per-wave private h region
  asm volatile("s_waitcnt vmcnt(0) lgkmcnt(0)" ::: "memory");
  __builtin_amdgcn_s_barrier();
  __builtin_amdgcn_sched_barrier(0);

  short* hW = reinterpret_cast<short*>(lds) + wv * 5376;  // 32 rows x 168
#pragma unroll
  for (int rf = 0; rf < 2; ++rf) {
#pragma unroll
    for (int cb = 0; cb < 10; ++cb) {
      int col = cb * 16 + l15;
      float bb = (col < HH) ? b1[col] : 0.f;
#pragma unroll
      for (int i = 0; i < 4; ++i) {
        int row = rf * 16 + kg * 4 + i;     // C layout: row=(l>>4)*4+i
        float v = fmaxf(acc[rf][cb][i] + bb, 0.f);
        hW[row * 168 + col] = f2bf(v);
      }
    }
  }
  // same-wave ds write->read is in-order; no barrier needed.

  f32x4 acc2[2][2];
  {
    f32x4 z = {0.f, 0.f, 0.f, 0.f};
#pragma unroll
    for (int rf = 0; rf < 2; ++rf) { acc2[rf][0] = z; acc2[rf][1] = z; }
  }
#pragma unroll
  for (int ks = 0; ks < 5; ++ks) {
#pragma unroll
    for (int cb2 = 0; cb2 < 2; ++cb2) {
      shortx8 wf = *reinterpret_cast<const shortx8*>(
          W2p + ((ks * 2 + cb2) * 64 + lane) * 8);
#pragma unroll
      for (int rf = 0; rf < 2; ++rf) {
        shortx8 af = *reinterpret_cast<const shortx8*>(
            reinterpret_cast<const char*>(hW) + (rf * 16 + l15) * 336 + ks * 64 + kg * 16);
        acc2[rf][cb2] = __builtin_amdgcn_mfma_f32_16x16x32_bf16(
            af, wf, acc2[rf][cb2], 0, 0, 0);
      }
    }
  }

#pragma unroll
  for (int rf = 0; rf < 2; ++rf) {
#pragma unroll
    for (int cb2 = 0; cb2 < 2; ++cb2) {
      int col = cb2 * 16 + l15;
      if (col < LL) {
        float bb = b2[col];
#pragma unroll
        for (int i = 0; i < 4; ++i) {
          int row = blk * 128 + wv * 32 + rf * 16 + kg * 4 + i;
          out[(size_t)row * LL + col] = acc2[rf][cb2][i] + bb;
        }
      }
    }
  }
#undef WAITSTAGE
}

extern "C" void kernel_launch(void* const* d_in, const int* in_sizes, int n_in,
                              void* d_out, int out_size, void* d_ws, size_t ws_size,
                              hipStream_t stream) {
  const float* xs    = (const float*)d_in[0];
  const int*   spans = (const int*)d_in[1];
  const int*   bids  = (const int*)d_in[2];
  const float* W1    = (const float*)d_in[3];
  const float* b1    = (const float*)d_in[4];
  const float* W2    = (const float*)d_in[5];
  const float* b2    = (const float*)d_in[6];
  float* out = (float*)d_out;

  const size_t XS16B = 33554432;            // 16,777,216 bf16
  const size_t WREQ  = XS16B + 655360 + 10240;

  if (ws_size >= WREQ) {
    short* xs16 = (short*)d_ws;
    short* Bp   = (short*)((char*)d_ws + XS16B);
    short* W2p  = Bp + 327680;
    prep_all<<<2211, 256, 0, stream>>>(xs, W1, W2, xs16, Bp, W2p, 1);
    span_mlp2<1><<<512, 256, 0, stream>>>(xs16, spans, bids, Bp, b1, W2p, b2, out);
  } else {
    short* Bp  = (short*)d_ws;
    short* W2p = Bp + 327680;
    prep_all<<<163, 256, 0, stream>>>(xs, W1, W2, nullptr, Bp, W2p, 0);
    span_mlp2<0><<<512, 256, 0, stream>>>(xs, spans, bids, Bp, b1, W2p, b2, out);
  }
}